// Round 7
// baseline (889.851 us; speedup 1.0000x reference)
//
#include <hip/hip_runtime.h>

#define NN 100000
#define EE 1600000
#define DD 64
#define CC 10
#define GG 512
#define LL 5
#define NPAD 100352            // 392*256
#define N64 (NN * DD)
#define NB 392                 // coarse buckets (256 nodes each)
#define PCH 4096               // edges per partition block
#define BCAP 6144              // per-bucket LDS capacity (mean 4082, >30 sigma)
#define SC 8                   // BN stats shadow copies

typedef short bf16x8 __attribute__((ext_vector_type(8)));
typedef float f32x4  __attribute__((ext_vector_type(4)));
union U16 { uint4 u; bf16x8 h; };

__device__ __forceinline__ float bits2f(unsigned int b) { return __uint_as_float(b); }
__device__ __forceinline__ float bf2f(unsigned short s) { return __uint_as_float((unsigned int)s << 16); }
__device__ __forceinline__ unsigned short f2bf_rne(float v) {
    unsigned int b = __float_as_uint(v);
    return (unsigned short)((b + 0x7fffu + ((b >> 16) & 1u)) >> 16);
}
__device__ __forceinline__ void unpack8(uint4 u, float* f) {
    f[0] = bits2f(u.x << 16); f[1] = bits2f(u.x & 0xffff0000u);
    f[2] = bits2f(u.y << 16); f[3] = bits2f(u.y & 0xffff0000u);
    f[4] = bits2f(u.z << 16); f[5] = bits2f(u.z & 0xffff0000u);
    f[6] = bits2f(u.w << 16); f[7] = bits2f(u.w & 0xffff0000u);
}
__device__ __forceinline__ uint4 pack8(const float* f) {
    uint4 u;
    u.x = (unsigned int)f2bf_rne(f[0]) | ((unsigned int)f2bf_rne(f[1]) << 16);
    u.y = (unsigned int)f2bf_rne(f[2]) | ((unsigned int)f2bf_rne(f[3]) << 16);
    u.z = (unsigned int)f2bf_rne(f[4]) | ((unsigned int)f2bf_rne(f[5]) << 16);
    u.w = (unsigned int)f2bf_rne(f[6]) | ((unsigned int)f2bf_rne(f[7]) << 16);
    return u;
}

// ======== prep: x fp32 -> bf16 h, fused layer-0 segmented pooling ========
__global__ __launch_bounds__(256) void prep_x_pool_k(
    const float* __restrict__ x, const int* __restrict__ batch,
    unsigned short* __restrict__ hb, float* __restrict__ pooled)
{
    int t = threadIdx.x;
    int f = t & 63;
    int q = t >> 6;
    int n0 = blockIdx.x * 64 + q * 16;
    int nmax = NN - n0; if (nmax > 16) nmax = 16;
    float acc = 0.f;
    int curg = -1;
    #pragma unroll 4
    for (int i = 0; i < nmax; ++i) {
        int n = n0 + i;
        int g = batch[n];
        if (g != curg) {
            if (curg >= 0) atomicAdd(&pooled[(size_t)curg * DD + f], acc);
            acc = 0.f; curg = g;
        }
        float v = x[(size_t)n * DD + f];
        hb[(size_t)n * DD + f] = f2bf_rne(v);
        acc += v;
    }
    if (curg >= 0) atomicAdd(&pooled[(size_t)curg * DD + f], acc);
}

// ================= prep: W -> transposed bf16 =================
__global__ __launch_bounds__(256) void prep_w_k(const float* __restrict__ W1,
                                                const float* __restrict__ W2,
                                                unsigned short* __restrict__ wt) {
    int mat = blockIdx.x;
    const float* src = (mat < 4) ? (W1 + (size_t)mat * 4096)
                                 : (W2 + (size_t)(mat - 4) * 4096);
    for (int idx = threadIdx.x; idx < 4096; idx += 256) {
        int c = idx >> 6, k = idx & 63;
        wt[(size_t)mat * 4096 + c * 64 + k] = f2bf_rne(src[k * 64 + c]);
    }
}

// ================= CSR build: coarse hist =================
__global__ __launch_bounds__(256) void bhist_k(const int* __restrict__ ei,
                                               int* __restrict__ bh) {
    __shared__ int cnt[NB];
    for (int i = threadIdx.x; i < NB; i += 256) cnt[i] = 0;
    __syncthreads();
    int stride = gridDim.x * 256;
    for (int e = blockIdx.x * 256 + threadIdx.x; e < EE; e += stride)
        atomicAdd(&cnt[ei[EE + e] >> 8], 1);
    __syncthreads();
    for (int i = threadIdx.x; i < NB; i += 256)
        if (cnt[i]) atomicAdd(&bh[i], cnt[i]);
}

// ================= coarse scan =================
__global__ __launch_bounds__(512) void bscan_k(const int* __restrict__ bh,
                                               int* __restrict__ bo,
                                               int* __restrict__ bcur) {
    __shared__ int s[512];
    int t = threadIdx.x;
    int v = (t < NB) ? bh[t] : 0;
    s[t] = v;
    __syncthreads();
    for (int d = 1; d < 512; d <<= 1) {
        int a = (t >= d) ? s[t - d] : 0;
        __syncthreads();
        s[t] += a;
        __syncthreads();
    }
    int excl = s[t] - v;
    if (t < NB) { bo[t] = excl; bcur[t] = excl; }
    if (t == NB - 1) bo[NB] = excl + v;
}

// ============ partition edges into bucket-contiguous staging ============
// stage entry: src (bits 0..16) | dst-local-in-bucket (bits 17..24)
__global__ __launch_bounds__(256) void partition_k(const int* __restrict__ ei,
                                                   int* __restrict__ bcur,
                                                   unsigned int* __restrict__ stage) {
    __shared__ int hist[NB];
    __shared__ int base[NB];
    __shared__ int gbase[NB];
    __shared__ int cnt2[NB];
    __shared__ int scanbuf[512];
    __shared__ unsigned int pairs[PCH];
    int t = threadIdx.x;
    int e0 = blockIdx.x * PCH;
    int nE = EE - e0; if (nE > PCH) nE = PCH;

    for (int i = t; i < NB; i += 256) { hist[i] = 0; cnt2[i] = 0; }
    __syncthreads();

    int mys[16], myd[16];
    #pragma unroll
    for (int i = 0; i < 16; ++i) {
        int idx = i * 256 + t;
        if (idx < nE) {
            mys[i] = ei[e0 + idx];
            myd[i] = ei[EE + e0 + idx];
            atomicAdd(&hist[myd[i] >> 8], 1);
        } else myd[i] = -1;
    }
    __syncthreads();

    scanbuf[t]       = (t < NB) ? hist[t] : 0;
    scanbuf[t + 256] = (t + 256 < NB) ? hist[t + 256] : 0;
    __syncthreads();
    for (int d = 1; d < 512; d <<= 1) {
        int a0 = (t >= d) ? scanbuf[t - d] : 0;
        int a1 = ((t + 256) >= d) ? scanbuf[t + 256 - d] : 0;
        __syncthreads();
        scanbuf[t] += a0;
        scanbuf[t + 256] += a1;
        __syncthreads();
    }
    if (t < NB)       base[t]       = scanbuf[t] - hist[t];
    if (t + 256 < NB) base[t + 256] = scanbuf[t + 256] - hist[t + 256];
    __syncthreads();

    #pragma unroll
    for (int i = 0; i < 16; ++i) {
        if (myd[i] >= 0) {
            int b = myd[i] >> 8;
            int p = base[b] + atomicAdd(&cnt2[b], 1);
            pairs[p] = (unsigned)mys[i] | ((unsigned)(myd[i] & 255) << 17);
        }
    }
    __syncthreads();
    for (int i = t; i < NB; i += 256)
        if (hist[i]) gbase[i] = atomicAdd(&bcur[i], hist[i]);
    __syncthreads();
    for (int p = t; p < nE; p += 256) {
        unsigned int pr = pairs[p];
        int b = -1;
        // bucket of this staged slot: find via base[]; instead recompute from dst-local? dst-local
        // alone doesn't give bucket, so locate by binary search over base[] is overkill —
        // we iterate buckets via a second pass: use the fact that slot p belongs to the
        // bucket whose [base[b], base[b]+hist[b]) contains p. Do a small linear scan in
        // LDS is too slow; instead stash bucket id in unused high bits (25..31): 7 bits
        // can't hold 392. So re-derive: we stored only dl. Write-out needs b.
        // Solution: overwrite pairs pass stored (dl<<17); we recover b by searching scanbuf
        // which holds inclusive prefix sums: p < scanbuf[b] and p >= scanbuf[b]-hist[b].
        // Binary search over 392 entries in LDS: 9 ds_reads.
        int lo = 0, hi = NB - 1;
        while (lo < hi) {
            int mid = (lo + hi) >> 1;
            if (p < scanbuf[mid]) hi = mid; else lo = mid + 1;
        }
        b = lo;
        stage[gbase[b] + (p - base[b])] = pr;
    }
}

// ============ per-bucket CSR: adj + offs, all in LDS ============
__global__ __launch_bounds__(256) void bucket_csr_k(const unsigned int* __restrict__ stage,
                                                    const int* __restrict__ bo,
                                                    int* __restrict__ adj,
                                                    int* __restrict__ offs) {
    __shared__ int deg[256];
    __shared__ int sb[256];
    __shared__ int nb_[256];
    __shared__ int c2[256];
    __shared__ int loc[BCAP];
    int b = blockIdx.x;
    int s0 = bo[b], s1 = bo[b + 1];
    int cnt = s1 - s0;
    int t = threadIdx.x;

    deg[t] = 0;
    __syncthreads();
    for (int i = t; i < cnt; i += 256) atomicAdd(&deg[(stage[s0 + i] >> 17) & 255], 1);
    __syncthreads();
    sb[t] = deg[t];
    __syncthreads();
    for (int d = 1; d < 256; d <<= 1) {
        int a = (t >= d) ? sb[t - d] : 0;
        __syncthreads();
        sb[t] += a;
        __syncthreads();
    }
    int nbase = sb[t] - deg[t];
    nb_[t] = nbase;
    c2[t] = 0;
    offs[b * 256 + t] = s0 + nbase;
    __syncthreads();

    if (cnt <= BCAP) {
        for (int i = t; i < cnt; i += 256) {
            unsigned int pr = stage[s0 + i];
            int ln = (pr >> 17) & 255;
            int p = nb_[ln] + atomicAdd(&c2[ln], 1);
            loc[p] = (int)(pr & 0x1FFFF);
        }
        __syncthreads();
        for (int i = t; i < cnt; i += 256) adj[s0 + i] = loc[i];
    } else {            // statistically unreachable fallback
        for (int i = t; i < cnt; i += 256) {
            unsigned int pr = stage[s0 + i];
            int ln = (pr >> 17) & 255;
            int p = nb_[ln] + atomicAdd(&c2[ln], 1);
            adj[s0 + p] = (int)(pr & 0x1FFFF);
        }
    }
}

// ========== K1: wave-per-node gather -> LDS -> MFMA GEMM1 + stats1 ==========
__global__ __launch_bounds__(256) void layer1_k(
    const unsigned short* __restrict__ hb, const int* __restrict__ adj,
    const int* __restrict__ offs, const float* __restrict__ epsArr, int l,
    const unsigned short* __restrict__ wtm, const float* __restrict__ bias,
    unsigned short* __restrict__ z1, float* __restrict__ stats1,
    float* __restrict__ stats2z)
{
    __shared__ unsigned short aLDS[64 * 64];   // 8KB, XOR-swizzled 16B units
    const int t = threadIdx.x;
    const int lane = t & 63;
    const int w = t >> 6;
    const int n15 = lane & 15;
    const int quad = lane >> 4;

    if (blockIdx.x < SC && t < 128) stats2z[blockIdx.x * 128 + t] = 0.f;

    const float epsv = 1.0f + epsArr[l];

    // ---- wave-per-node gather: wave w owns rows w*16 .. w*16+15 ----
    for (int i = 0; i < 16; ++i) {
        int lr = w * 16 + i;
        int n = blockIdx.x * 64 + lr;
        float acc = 0.f;
        if (n < NN) {
            acc = epsv * bf2f(hb[(size_t)n * DD + lane]);
            int j = __builtin_amdgcn_readfirstlane(offs[n]);
            int end = __builtin_amdgcn_readfirstlane(offs[n + 1]);
            while (j < end) {
                int cnt = end - j; if (cnt > 16) cnt = 16;
                int idx = j + n15; if (idx >= end) idx = end - 1;
                int myadj = adj[idx];          // 16-lane coalesced index load
                #pragma unroll
                for (int k = 0; k < 16; ++k) {
                    if (k < cnt) {             // wave-uniform guard
                        int s = __builtin_amdgcn_readlane(myadj, k);
                        acc += bf2f(hb[(size_t)s * DD + lane]);  // 128B coalesced row
                    }
                }
                j += cnt;
            }
        }
        int u = (lane >> 3) ^ (lr & 7);        // 16B-unit XOR swizzle
        aLDS[lr * 64 + u * 8 + (lane & 7)] = f2bf_rne(acc);
    }
    // rows are wave-private; no barrier needed (compiler inserts lgkmcnt)

    // ---- A fragments from LDS (swizzled) ----
    U16 afr[2];
    int lr2 = w * 16 + n15;
    #pragma unroll
    for (int ks = 0; ks < 2; ++ks) {
        int pu = (ks * 4 + quad) ^ (lr2 & 7);
        afr[ks].u = *(const uint4*)(aLDS + lr2 * 64 + pu * 8);
    }
    // ---- B fragments from global ----
    U16 bfr[4][2];
    #pragma unroll
    for (int ct = 0; ct < 4; ++ct)
        #pragma unroll
        for (int ks = 0; ks < 2; ++ks)
            bfr[ct][ks].u = *(const uint4*)(wtm + (size_t)(ct * 16 + n15) * 64 + ks * 32 + quad * 8);

    const int rowg0 = blockIdx.x * 64 + w * 16;
    const int copy = blockIdx.x & (SC - 1);
    #pragma unroll
    for (int ct = 0; ct < 4; ++ct) {
        f32x4 acc = {0.f, 0.f, 0.f, 0.f};
        acc = __builtin_amdgcn_mfma_f32_16x16x32_bf16(afr[0].h, bfr[ct][0].h, acc, 0, 0, 0);
        acc = __builtin_amdgcn_mfma_f32_16x16x32_bf16(afr[1].h, bfr[ct][1].h, acc, 0, 0, 0);
        int col = ct * 16 + n15;
        float bcol = bias[col];
        float s = 0.f, ss = 0.f;
        #pragma unroll
        for (int r = 0; r < 4; ++r) {
            int rg = rowg0 + quad * 4 + r;
            float v = acc[r] + bcol;
            if (rg < NN) {
                z1[(size_t)rg * DD + col] = f2bf_rne(v);
                s += v;
                ss = fmaf(v, v, ss);
            }
        }
        s  += __shfl_xor(s, 16, 64);  s  += __shfl_xor(s, 32, 64);
        ss += __shfl_xor(ss, 16, 64); ss += __shfl_xor(ss, 32, 64);
        if (lane < 16) {
            atomicAdd(&stats1[copy * 128 + ct * 16 + lane], s);
            atomicAdd(&stats1[copy * 128 + 64 + ct * 16 + lane], ss);
        }
    }
}

// ========== K2: inline BN1 + MFMA GEMM2 + stats2 ==========
__global__ __launch_bounds__(256) void layer2_k(
    const unsigned short* __restrict__ z1, const float* __restrict__ stats1,
    const float* __restrict__ gamma, const float* __restrict__ beta, int off,
    const unsigned short* __restrict__ wtm, const float* __restrict__ bias,
    unsigned short* __restrict__ z2, float* __restrict__ stats2)
{
    __shared__ float ssS[128];
    const int t = threadIdx.x;
    if (t < 64) {
        float S = 0.f, SS = 0.f;
        #pragma unroll
        for (int c = 0; c < SC; ++c) { S += stats1[c * 128 + t]; SS += stats1[c * 128 + 64 + t]; }
        float inv_n = 1.0f / (float)NN;
        float mean = S * inv_n;
        float var  = SS * inv_n - mean * mean;
        float sc = gamma[off + t] * rsqrtf(var + 1e-5f);
        ssS[t] = sc;
        ssS[64 + t] = beta[off + t] - sc * mean;
    }
    __syncthreads();

    const int lane = t & 63;
    const int w = t >> 6;
    const int n15 = lane & 15;
    const int quad = lane >> 4;
    const int rowg0 = blockIdx.x * 64 + w * 16;

    U16 bfr[4][2];
    #pragma unroll
    for (int ct = 0; ct < 4; ++ct)
        #pragma unroll
        for (int ks = 0; ks < 2; ++ks)
            bfr[ct][ks].u = *(const uint4*)(wtm + (size_t)(ct * 16 + n15) * 64 + ks * 32 + quad * 8);

    U16 afr[2];
    int arow = rowg0 + n15;
    int arowc = (arow < NN) ? arow : (NN - 1);
    #pragma unroll
    for (int ks = 0; ks < 2; ++ks) {
        uint4 raw = *(const uint4*)(z1 + (size_t)arowc * DD + ks * 32 + quad * 8);
        float f[8];
        unpack8(raw, f);
        int k0 = ks * 32 + quad * 8;
        #pragma unroll
        for (int j = 0; j < 8; ++j)
            f[j] = fmaxf(fmaf(ssS[k0 + j], f[j], ssS[64 + k0 + j]), 0.f);
        afr[ks].u = pack8(f);
    }

    const int copy = blockIdx.x & (SC - 1);
    #pragma unroll
    for (int ct = 0; ct < 4; ++ct) {
        f32x4 acc = {0.f, 0.f, 0.f, 0.f};
        acc = __builtin_amdgcn_mfma_f32_16x16x32_bf16(afr[0].h, bfr[ct][0].h, acc, 0, 0, 0);
        acc = __builtin_amdgcn_mfma_f32_16x16x32_bf16(afr[1].h, bfr[ct][1].h, acc, 0, 0, 0);
        int col = ct * 16 + n15;
        float bcol = bias[col];
        float s = 0.f, ss = 0.f;
        #pragma unroll
        for (int r = 0; r < 4; ++r) {
            int rg = rowg0 + quad * 4 + r;
            float v = acc[r] + bcol;
            if (rg < NN) {
                z2[(size_t)rg * DD + col] = f2bf_rne(v);
                s += v;
                ss = fmaf(v, v, ss);
            }
        }
        s  += __shfl_xor(s, 16, 64);  s  += __shfl_xor(s, 32, 64);
        ss += __shfl_xor(ss, 16, 64); ss += __shfl_xor(ss, 32, 64);
        if (lane < 16) {
            atomicAdd(&stats2[copy * 128 + ct * 16 + lane], s);
            atomicAdd(&stats2[copy * 128 + 64 + ct * 16 + lane], ss);
        }
    }
}

// ========== K3: inline BN2 + ReLU + hb write + segmented pool ==========
__global__ __launch_bounds__(256) void layer3_k(
    const unsigned short* __restrict__ z2, const float* __restrict__ stats2,
    const float* __restrict__ gamma, const float* __restrict__ beta, int off,
    const int* __restrict__ batch, unsigned short* __restrict__ hout,
    float* __restrict__ pooled, float* __restrict__ stats1z)
{
    __shared__ float ssS[128];
    int t = threadIdx.x;
    if (blockIdx.x < SC && t < 128) stats1z[blockIdx.x * 128 + t] = 0.f;
    if (t < 64) {
        float S = 0.f, SS = 0.f;
        #pragma unroll
        for (int c = 0; c < SC; ++c) { S += stats2[c * 128 + t]; SS += stats2[c * 128 + 64 + t]; }
        float inv_n = 1.0f / (float)NN;
        float mean = S * inv_n;
        float var  = SS * inv_n - mean * mean;
        float sc = gamma[off + t] * rsqrtf(var + 1e-5f);
        ssS[t] = sc;
        ssS[64 + t] = beta[off + t] - sc * mean;
    }
    __syncthreads();

    int f = t & 63;
    int q = t >> 6;
    int n0 = blockIdx.x * 64 + q * 16;
    int nmax = NN - n0; if (nmax > 16) nmax = 16;
    float sc = ssS[f], sh = ssS[64 + f];
    float acc = 0.f;
    int curg = -1;
    #pragma unroll 4
    for (int i = 0; i < nmax; ++i) {
        int n = n0 + i;
        int g = batch[n];
        if (g != curg) {
            if (curg >= 0) atomicAdd(&pooled[(size_t)curg * DD + f], acc);
            acc = 0.f; curg = g;
        }
        float v = bf2f(z2[(size_t)n * DD + f]);
        v = fmaxf(fmaf(sc, v, sh), 0.f);
        hout[(size_t)n * DD + f] = f2bf_rne(v);
        acc += v;
    }
    if (curg >= 0) atomicAdd(&pooled[(size_t)curg * DD + f], acc);
}

// ================= jumping-knowledge readout =================
__global__ void readout_k(const float* __restrict__ pooled,
                          const float* __restrict__ Wp, const float* __restrict__ bp,
                          float* __restrict__ out)
{
    int gc = blockIdx.x * blockDim.x + threadIdx.x;
    if (gc >= GG * CC) return;
    int g = gc / CC, c = gc - g * CC;
    float acc = 0.f;
    for (int l = 0; l < LL; ++l) {
        acc += bp[l * CC + c];
        const float* p  = pooled + ((size_t)l * GG + g) * DD;
        const float* wv = Wp + (size_t)l * DD * CC + c;
        #pragma unroll 8
        for (int f = 0; f < DD; ++f) acc = fmaf(p[f], wv[f * CC], acc);
    }
    out[gc] = acc;
}

extern "C" void kernel_launch(void* const* d_in, const int* in_sizes, int n_in,
                              void* d_out, int out_size, void* d_ws, size_t ws_size,
                              hipStream_t stream) {
    const float* x     = (const float*)d_in[0];
    const int*   ei    = (const int*)d_in[1];
    const int*   batch = (const int*)d_in[2];
    const float* eps   = (const float*)d_in[3];
    const float* W1    = (const float*)d_in[4];
    const float* b1    = (const float*)d_in[5];
    const float* g1    = (const float*)d_in[6];
    const float* be1   = (const float*)d_in[7];
    const float* W2    = (const float*)d_in[8];
    const float* b2    = (const float*)d_in[9];
    const float* gout  = (const float*)d_in[10];
    const float* beout = (const float*)d_in[11];
    const float* Wp    = (const float*)d_in[12];
    const float* bp    = (const float*)d_in[13];
    float* out = (float*)d_out;

    // ---- workspace layout (16B-aligned sections) ----
    unsigned int* stage = (unsigned int*)d_ws;          // EE*4
    int* adj   = (int*)(stage + EE);                    // EE*4
    int* offs  = adj + EE;                              // (NPAD+256)
    int* bh    = offs + NPAD + 256;                     // 400
    int* bo    = bh + 400;                              // 400
    int* bcur  = bo + 400;                              // 400
    float* pooled = (float*)(bcur + 400);               // LL*GG*DD
    float* stats1 = pooled + (size_t)LL * GG * DD;      // SC*128
    float* stats2 = stats1 + SC * 128;                  // SC*128
    unsigned short* hb  = (unsigned short*)(stats2 + SC * 128);
    unsigned short* z1b = hb + N64;
    unsigned short* z2b = z1b + N64;
    unsigned short* wt  = z2b + N64;                    // 8*4096

    // ---- prep + layer-0 pooling ----
    hipMemsetAsync(pooled, 0, ((size_t)LL * GG * DD + 2 * SC * 128) * sizeof(float), stream);
    prep_x_pool_k<<<(NN + 63) / 64, 256, 0, stream>>>(x, batch, hb, pooled);
    prep_w_k<<<8, 256, 0, stream>>>(W1, W2, wt);

    // ---- CSR build via LDS-staged two-pass partition ----
    hipMemsetAsync(bh, 0, NB * sizeof(int), stream);
    bhist_k<<<512, 256, 0, stream>>>(ei, bh);
    bscan_k<<<1, 512, 0, stream>>>(bh, bo, bcur);
    partition_k<<<(EE + PCH - 1) / PCH, 256, 0, stream>>>(ei, bcur, stage);
    bucket_csr_k<<<NB, 256, 0, stream>>>(stage, bo, adj, offs);

    const int gemm_grid = (NN + 63) / 64;
    const int node_grid = (NN + 63) / 64;
    for (int l = 0; l < LL - 1; ++l) {
        layer1_k<<<gemm_grid, 256, 0, stream>>>(
            hb, adj, offs, eps, l, wt + (size_t)l * 4096, b1 + l * DD, z1b, stats1, stats2);
        layer2_k<<<gemm_grid, 256, 0, stream>>>(
            z1b, stats1, g1, be1, l * DD, wt + (size_t)(4 + l) * 4096, b2 + l * DD, z2b, stats2);
        layer3_k<<<node_grid, 256, 0, stream>>>(
            z2b, stats2, gout, beout, l * DD, batch, hb,
            pooled + (size_t)(l + 1) * GG * DD, stats1);
    }
    readout_k<<<(GG * CC + 255) / 256, 256, 0, stream>>>(pooled, Wp, bp, out);
}

// Round 8
// 697.379 us; speedup vs baseline: 1.2760x; 1.2760x over previous
//
#include <hip/hip_runtime.h>

#define NN 100000
#define EE 1600000
#define DD 64
#define CC 10
#define GG 512
#define LL 5
#define NPAD 100352            // 392*256
#define N64 (NN * DD)
#define NB 392                 // coarse buckets (256 nodes each)
#define PCH 4096               // edges per partition block
#define BCAP 6144              // per-bucket LDS capacity (mean 4082, >30 sigma)
#define SC 8                   // BN stats shadow copies

typedef short bf16x8 __attribute__((ext_vector_type(8)));
typedef float f32x4  __attribute__((ext_vector_type(4)));
union U16 { uint4 u; bf16x8 h; };

__device__ __forceinline__ float bits2f(unsigned int b) { return __uint_as_float(b); }
__device__ __forceinline__ float bf2f(unsigned short s) { return __uint_as_float((unsigned int)s << 16); }
__device__ __forceinline__ unsigned short f2bf_rne(float v) {
    unsigned int b = __float_as_uint(v);
    return (unsigned short)((b + 0x7fffu + ((b >> 16) & 1u)) >> 16);
}
__device__ __forceinline__ void unpack8(uint4 u, float* f) {
    f[0] = bits2f(u.x << 16); f[1] = bits2f(u.x & 0xffff0000u);
    f[2] = bits2f(u.y << 16); f[3] = bits2f(u.y & 0xffff0000u);
    f[4] = bits2f(u.z << 16); f[5] = bits2f(u.z & 0xffff0000u);
    f[6] = bits2f(u.w << 16); f[7] = bits2f(u.w & 0xffff0000u);
}
__device__ __forceinline__ uint4 pack8(const float* f) {
    uint4 u;
    u.x = (unsigned int)f2bf_rne(f[0]) | ((unsigned int)f2bf_rne(f[1]) << 16);
    u.y = (unsigned int)f2bf_rne(f[2]) | ((unsigned int)f2bf_rne(f[3]) << 16);
    u.z = (unsigned int)f2bf_rne(f[4]) | ((unsigned int)f2bf_rne(f[5]) << 16);
    u.w = (unsigned int)f2bf_rne(f[6]) | ((unsigned int)f2bf_rne(f[7]) << 16);
    return u;
}
__device__ __forceinline__ void acc8(uint4 u, float* a) {
    float t[8];
    unpack8(u, t);
    #pragma unroll
    for (int k = 0; k < 8; ++k) a[k] += t[k];
}

// ======== prep: x fp32 -> bf16 h, fused layer-0 segmented pooling ========
__global__ __launch_bounds__(256) void prep_x_pool_k(
    const float* __restrict__ x, const int* __restrict__ batch,
    unsigned short* __restrict__ hb, float* __restrict__ pooled)
{
    int t = threadIdx.x;
    int f = t & 63;
    int q = t >> 6;
    int n0 = blockIdx.x * 64 + q * 16;
    int nmax = NN - n0; if (nmax > 16) nmax = 16;
    float acc = 0.f;
    int curg = -1;
    #pragma unroll 4
    for (int i = 0; i < nmax; ++i) {
        int n = n0 + i;
        int g = batch[n];
        if (g != curg) {
            if (curg >= 0) atomicAdd(&pooled[(size_t)curg * DD + f], acc);
            acc = 0.f; curg = g;
        }
        float v = x[(size_t)n * DD + f];
        hb[(size_t)n * DD + f] = f2bf_rne(v);
        acc += v;
    }
    if (curg >= 0) atomicAdd(&pooled[(size_t)curg * DD + f], acc);
}

// ================= prep: W -> transposed bf16 =================
__global__ __launch_bounds__(256) void prep_w_k(const float* __restrict__ W1,
                                                const float* __restrict__ W2,
                                                unsigned short* __restrict__ wt) {
    int mat = blockIdx.x;
    const float* src = (mat < 4) ? (W1 + (size_t)mat * 4096)
                                 : (W2 + (size_t)(mat - 4) * 4096);
    for (int idx = threadIdx.x; idx < 4096; idx += 256) {
        int c = idx >> 6, k = idx & 63;
        wt[(size_t)mat * 4096 + c * 64 + k] = f2bf_rne(src[k * 64 + c]);
    }
}

// ================= CSR build: coarse hist =================
__global__ __launch_bounds__(256) void bhist_k(const int* __restrict__ ei,
                                               int* __restrict__ bh) {
    __shared__ int cnt[NB];
    for (int i = threadIdx.x; i < NB; i += 256) cnt[i] = 0;
    __syncthreads();
    int stride = gridDim.x * 256;
    for (int e = blockIdx.x * 256 + threadIdx.x; e < EE; e += stride)
        atomicAdd(&cnt[ei[EE + e] >> 8], 1);
    __syncthreads();
    for (int i = threadIdx.x; i < NB; i += 256)
        if (cnt[i]) atomicAdd(&bh[i], cnt[i]);
}

// ================= coarse scan =================
__global__ __launch_bounds__(512) void bscan_k(const int* __restrict__ bh,
                                               int* __restrict__ bo,
                                               int* __restrict__ bcur) {
    __shared__ int s[512];
    int t = threadIdx.x;
    int v = (t < NB) ? bh[t] : 0;
    s[t] = v;
    __syncthreads();
    for (int d = 1; d < 512; d <<= 1) {
        int a = (t >= d) ? s[t - d] : 0;
        __syncthreads();
        s[t] += a;
        __syncthreads();
    }
    int excl = s[t] - v;
    if (t < NB) { bo[t] = excl; bcur[t] = excl; }
    if (t == NB - 1) bo[NB] = excl + v;
}

// ============ partition edges into bucket-contiguous staging ============
// stage entry: src (bits 0..16) | dst-local-in-bucket (bits 17..24)
__global__ __launch_bounds__(256) void partition_k(const int* __restrict__ ei,
                                                   int* __restrict__ bcur,
                                                   unsigned int* __restrict__ stage) {
    __shared__ int hist[NB];
    __shared__ int base[NB];
    __shared__ int gbase[NB];
    __shared__ int cnt2[NB];
    __shared__ int scanbuf[512];
    __shared__ unsigned int pairs[PCH];
    __shared__ unsigned short pbkt[PCH];
    int t = threadIdx.x;
    int e0 = blockIdx.x * PCH;
    int nE = EE - e0; if (nE > PCH) nE = PCH;

    for (int i = t; i < NB; i += 256) { hist[i] = 0; cnt2[i] = 0; }
    __syncthreads();

    int mys[16], myd[16];
    #pragma unroll
    for (int i = 0; i < 16; ++i) {
        int idx = i * 256 + t;
        if (idx < nE) {
            mys[i] = ei[e0 + idx];
            myd[i] = ei[EE + e0 + idx];
            atomicAdd(&hist[myd[i] >> 8], 1);
        } else myd[i] = -1;
    }
    __syncthreads();

    scanbuf[t]       = (t < NB) ? hist[t] : 0;
    scanbuf[t + 256] = (t + 256 < NB) ? hist[t + 256] : 0;
    __syncthreads();
    for (int d = 1; d < 512; d <<= 1) {
        int a0 = (t >= d) ? scanbuf[t - d] : 0;
        int a1 = ((t + 256) >= d) ? scanbuf[t + 256 - d] : 0;
        __syncthreads();
        scanbuf[t] += a0;
        scanbuf[t + 256] += a1;
        __syncthreads();
    }
    if (t < NB)       base[t]       = scanbuf[t] - hist[t];
    if (t + 256 < NB) base[t + 256] = scanbuf[t + 256] - hist[t + 256];
    __syncthreads();

    #pragma unroll
    for (int i = 0; i < 16; ++i) {
        if (myd[i] >= 0) {
            int b = myd[i] >> 8;
            int p = base[b] + atomicAdd(&cnt2[b], 1);
            pairs[p] = (unsigned)mys[i] | ((unsigned)(myd[i] & 255) << 17);
            pbkt[p] = (unsigned short)b;
        }
    }
    __syncthreads();
    for (int i = t; i < NB; i += 256)
        if (hist[i]) gbase[i] = atomicAdd(&bcur[i], hist[i]);
    __syncthreads();
    for (int p = t; p < nE; p += 256) {
        int b = pbkt[p];
        stage[gbase[b] + (p - base[b])] = pairs[p];
    }
}

// ============ per-bucket CSR: adj + offs, all in LDS ============
__global__ __launch_bounds__(256) void bucket_csr_k(const unsigned int* __restrict__ stage,
                                                    const int* __restrict__ bo,
                                                    int* __restrict__ adj,
                                                    int* __restrict__ offs) {
    __shared__ int deg[256];
    __shared__ int sb[256];
    __shared__ int nb_[256];
    __shared__ int c2[256];
    __shared__ int loc[BCAP];
    int b = blockIdx.x;
    int s0 = bo[b], s1 = bo[b + 1];
    int cnt = s1 - s0;
    int t = threadIdx.x;

    deg[t] = 0;
    __syncthreads();
    for (int i = t; i < cnt; i += 256) atomicAdd(&deg[(stage[s0 + i] >> 17) & 255], 1);
    __syncthreads();
    sb[t] = deg[t];
    __syncthreads();
    for (int d = 1; d < 256; d <<= 1) {
        int a = (t >= d) ? sb[t - d] : 0;
        __syncthreads();
        sb[t] += a;
        __syncthreads();
    }
    int nbase = sb[t] - deg[t];
    nb_[t] = nbase;
    c2[t] = 0;
    offs[b * 256 + t] = s0 + nbase;
    __syncthreads();

    if (cnt <= BCAP) {
        for (int i = t; i < cnt; i += 256) {
            unsigned int pr = stage[s0 + i];
            int ln = (pr >> 17) & 255;
            int p = nb_[ln] + atomicAdd(&c2[ln], 1);
            loc[p] = (int)(pr & 0x1FFFF);
        }
        __syncthreads();
        for (int i = t; i < cnt; i += 256) adj[s0 + i] = loc[i];
    } else {            // statistically unreachable fallback
        for (int i = t; i < cnt; i += 256) {
            unsigned int pr = stage[s0 + i];
            int ln = (pr >> 17) & 255;
            int p = nb_[ln] + atomicAdd(&c2[ln], 1);
            adj[s0 + p] = (int)(pr & 0x1FFFF);
        }
    }
}

// ========== K1: tandem 8-lane-group gather -> LDS -> MFMA GEMM1 + stats1 ==========
__global__ __launch_bounds__(256) void layer1_k(
    const unsigned short* __restrict__ hb, const int* __restrict__ adj,
    const int* __restrict__ offs, const float* __restrict__ epsArr, int l,
    const unsigned short* __restrict__ wtm, const float* __restrict__ bias,
    unsigned short* __restrict__ z1, float* __restrict__ stats1,
    float* __restrict__ stats2z)
{
    __shared__ unsigned short aLDS[64 * 64];   // 8KB, XOR-swizzled 16B units
    const int t = threadIdx.x;
    const int lane = t & 63;
    const int w = t >> 6;
    const int n15 = lane & 15;
    const int quad = lane >> 4;

    if (blockIdx.x < SC && t < 128) stats2z[blockIdx.x * 128 + t] = 0.f;

    // ---- B fragments + stats zero issued early (overlap the gather) ----
    U16 bfr[4][2];
    #pragma unroll
    for (int ct = 0; ct < 4; ++ct)
        #pragma unroll
        for (int ks = 0; ks < 2; ++ks)
            bfr[ct][ks].u = *(const uint4*)(wtm + (size_t)(ct * 16 + n15) * 64 + ks * 32 + quad * 8);

    const float epsv = 1.0f + epsArr[l];
    const int g8 = lane >> 3;
    const int c8 = lane & 7;

    // ---- tandem gather: group g8 owns rows g8 and g8+8 of this wave's 16 ----
    const int lr0 = w * 16 + g8;
    const int lr1 = lr0 + 8;
    const int nA = blockIdx.x * 64 + lr0;
    const int nB = nA + 8;
    float accA[8] = {0.f,0.f,0.f,0.f,0.f,0.f,0.f,0.f};
    float accB[8] = {0.f,0.f,0.f,0.f,0.f,0.f,0.f,0.f};
    int jA = 0, eA = 0, jB = 0, eB = 0;
    if (nA < NN) {
        uint4 a = *(const uint4*)(hb + (size_t)nA * DD + c8 * 8);
        jA = offs[nA]; eA = offs[nA + 1];
        unpack8(a, accA);
        #pragma unroll
        for (int k = 0; k < 8; ++k) accA[k] *= epsv;
    }
    if (nB < NN) {
        uint4 a = *(const uint4*)(hb + (size_t)nB * DD + c8 * 8);
        jB = offs[nB]; eB = offs[nB + 1];
        unpack8(a, accB);
        #pragma unroll
        for (int k = 0; k < 8; ++k) accB[k] *= epsv;
    }
    // tandem main loop: 4 independent row loads in flight per group
    for (; jA + 1 < eA && jB + 1 < eB; jA += 2, jB += 2) {
        int sA0 = adj[jA], sA1 = adj[jA + 1];
        int sB0 = adj[jB], sB1 = adj[jB + 1];
        uint4 vA0 = *(const uint4*)(hb + (size_t)sA0 * DD + c8 * 8);
        uint4 vA1 = *(const uint4*)(hb + (size_t)sA1 * DD + c8 * 8);
        uint4 vB0 = *(const uint4*)(hb + (size_t)sB0 * DD + c8 * 8);
        uint4 vB1 = *(const uint4*)(hb + (size_t)sB1 * DD + c8 * 8);
        acc8(vA0, accA); acc8(vA1, accA);
        acc8(vB0, accB); acc8(vB1, accB);
    }
    // row-A remainder
    for (; jA + 1 < eA; jA += 2) {
        int s0 = adj[jA], s1 = adj[jA + 1];
        uint4 v0 = *(const uint4*)(hb + (size_t)s0 * DD + c8 * 8);
        uint4 v1 = *(const uint4*)(hb + (size_t)s1 * DD + c8 * 8);
        acc8(v0, accA); acc8(v1, accA);
    }
    if (jA < eA) {
        uint4 v0 = *(const uint4*)(hb + (size_t)adj[jA] * DD + c8 * 8);
        acc8(v0, accA);
    }
    // row-B remainder
    for (; jB + 1 < eB; jB += 2) {
        int s0 = adj[jB], s1 = adj[jB + 1];
        uint4 v0 = *(const uint4*)(hb + (size_t)s0 * DD + c8 * 8);
        uint4 v1 = *(const uint4*)(hb + (size_t)s1 * DD + c8 * 8);
        acc8(v0, accB); acc8(v1, accB);
    }
    if (jB < eB) {
        uint4 v0 = *(const uint4*)(hb + (size_t)adj[jB] * DD + c8 * 8);
        acc8(v0, accB);
    }
    {
        int u0 = c8 ^ (lr0 & 7);
        *(uint4*)(aLDS + lr0 * 64 + u0 * 8) = pack8(accA);
        int u1 = c8 ^ (lr1 & 7);
        *(uint4*)(aLDS + lr1 * 64 + u1 * 8) = pack8(accB);
    }
    // rows are wave-private; compiler inserts lgkmcnt before the reads below

    // ---- A fragments from LDS (swizzled) ----
    U16 afr[2];
    int lr2 = w * 16 + n15;
    #pragma unroll
    for (int ks = 0; ks < 2; ++ks) {
        int pu = (ks * 4 + quad) ^ (lr2 & 7);
        afr[ks].u = *(const uint4*)(aLDS + lr2 * 64 + pu * 8);
    }

    const int rowg0 = blockIdx.x * 64 + w * 16;
    const int copy = blockIdx.x & (SC - 1);
    #pragma unroll
    for (int ct = 0; ct < 4; ++ct) {
        f32x4 acc = {0.f, 0.f, 0.f, 0.f};
        acc = __builtin_amdgcn_mfma_f32_16x16x32_bf16(afr[0].h, bfr[ct][0].h, acc, 0, 0, 0);
        acc = __builtin_amdgcn_mfma_f32_16x16x32_bf16(afr[1].h, bfr[ct][1].h, acc, 0, 0, 0);
        int col = ct * 16 + n15;
        float bcol = bias[col];
        float s = 0.f, ss = 0.f;
        #pragma unroll
        for (int r = 0; r < 4; ++r) {
            int rg = rowg0 + quad * 4 + r;
            float v = acc[r] + bcol;
            if (rg < NN) {
                z1[(size_t)rg * DD + col] = f2bf_rne(v);
                s += v;
                ss = fmaf(v, v, ss);
            }
        }
        s  += __shfl_xor(s, 16, 64);  s  += __shfl_xor(s, 32, 64);
        ss += __shfl_xor(ss, 16, 64); ss += __shfl_xor(ss, 32, 64);
        if (lane < 16) {
            atomicAdd(&stats1[copy * 128 + ct * 16 + lane], s);
            atomicAdd(&stats1[copy * 128 + 64 + ct * 16 + lane], ss);
        }
    }
}

// ========== K2: inline BN1 + MFMA GEMM2 + stats2 ==========
__global__ __launch_bounds__(256) void layer2_k(
    const unsigned short* __restrict__ z1, const float* __restrict__ stats1,
    const float* __restrict__ gamma, const float* __restrict__ beta, int off,
    const unsigned short* __restrict__ wtm, const float* __restrict__ bias,
    unsigned short* __restrict__ z2, float* __restrict__ stats2)
{
    __shared__ float ssS[128];
    const int t = threadIdx.x;
    if (t < 64) {
        float S = 0.f, SS = 0.f;
        #pragma unroll
        for (int c = 0; c < SC; ++c) { S += stats1[c * 128 + t]; SS += stats1[c * 128 + 64 + t]; }
        float inv_n = 1.0f / (float)NN;
        float mean = S * inv_n;
        float var  = SS * inv_n - mean * mean;
        float sc = gamma[off + t] * rsqrtf(var + 1e-5f);
        ssS[t] = sc;
        ssS[64 + t] = beta[off + t] - sc * mean;
    }
    __syncthreads();

    const int lane = t & 63;
    const int w = t >> 6;
    const int n15 = lane & 15;
    const int quad = lane >> 4;
    const int rowg0 = blockIdx.x * 64 + w * 16;

    U16 bfr[4][2];
    #pragma unroll
    for (int ct = 0; ct < 4; ++ct)
        #pragma unroll
        for (int ks = 0; ks < 2; ++ks)
            bfr[ct][ks].u = *(const uint4*)(wtm + (size_t)(ct * 16 + n15) * 64 + ks * 32 + quad * 8);

    U16 afr[2];
    int arow = rowg0 + n15;
    int arowc = (arow < NN) ? arow : (NN - 1);
    #pragma unroll
    for (int ks = 0; ks < 2; ++ks) {
        uint4 raw = *(const uint4*)(z1 + (size_t)arowc * DD + ks * 32 + quad * 8);
        float f[8];
        unpack8(raw, f);
        int k0 = ks * 32 + quad * 8;
        #pragma unroll
        for (int j = 0; j < 8; ++j)
            f[j] = fmaxf(fmaf(ssS[k0 + j], f[j], ssS[64 + k0 + j]), 0.f);
        afr[ks].u = pack8(f);
    }

    const int copy = blockIdx.x & (SC - 1);
    #pragma unroll
    for (int ct = 0; ct < 4; ++ct) {
        f32x4 acc = {0.f, 0.f, 0.f, 0.f};
        acc = __builtin_amdgcn_mfma_f32_16x16x32_bf16(afr[0].h, bfr[ct][0].h, acc, 0, 0, 0);
        acc = __builtin_amdgcn_mfma_f32_16x16x32_bf16(afr[1].h, bfr[ct][1].h, acc, 0, 0, 0);
        int col = ct * 16 + n15;
        float bcol = bias[col];
        float s = 0.f, ss = 0.f;
        #pragma unroll
        for (int r = 0; r < 4; ++r) {
            int rg = rowg0 + quad * 4 + r;
            float v = acc[r] + bcol;
            if (rg < NN) {
                z2[(size_t)rg * DD + col] = f2bf_rne(v);
                s += v;
                ss = fmaf(v, v, ss);
            }
        }
        s  += __shfl_xor(s, 16, 64);  s  += __shfl_xor(s, 32, 64);
        ss += __shfl_xor(ss, 16, 64); ss += __shfl_xor(ss, 32, 64);
        if (lane < 16) {
            atomicAdd(&stats2[copy * 128 + ct * 16 + lane], s);
            atomicAdd(&stats2[copy * 128 + 64 + ct * 16 + lane], ss);
        }
    }
}

// ========== K3: inline BN2 + ReLU + hb write + segmented pool ==========
__global__ __launch_bounds__(256) void layer3_k(
    const unsigned short* __restrict__ z2, const float* __restrict__ stats2,
    const float* __restrict__ gamma, const float* __restrict__ beta, int off,
    const int* __restrict__ batch, unsigned short* __restrict__ hout,
    float* __restrict__ pooled, float* __restrict__ stats1z)
{
    __shared__ float ssS[128];
    int t = threadIdx.x;
    if (blockIdx.x < SC && t < 128) stats1z[blockIdx.x * 128 + t] = 0.f;
    if (t < 64) {
        float S = 0.f, SS = 0.f;
        #pragma unroll
        for (int c = 0; c < SC; ++c) { S += stats2[c * 128 + t]; SS += stats2[c * 128 + 64 + t]; }
        float inv_n = 1.0f / (float)NN;
        float mean = S * inv_n;
        float var  = SS * inv_n - mean * mean;
        float sc = gamma[off + t] * rsqrtf(var + 1e-5f);
        ssS[t] = sc;
        ssS[64 + t] = beta[off + t] - sc * mean;
    }
    __syncthreads();

    int f = t & 63;
    int q = t >> 6;
    int n0 = blockIdx.x * 64 + q * 16;
    int nmax = NN - n0; if (nmax > 16) nmax = 16;
    float sc = ssS[f], sh = ssS[64 + f];
    float acc = 0.f;
    int curg = -1;
    #pragma unroll 4
    for (int i = 0; i < nmax; ++i) {
        int n = n0 + i;
        int g = batch[n];
        if (g != curg) {
            if (curg >= 0) atomicAdd(&pooled[(size_t)curg * DD + f], acc);
            acc = 0.f; curg = g;
        }
        float v = bf2f(z2[(size_t)n * DD + f]);
        v = fmaxf(fmaf(sc, v, sh), 0.f);
        hout[(size_t)n * DD + f] = f2bf_rne(v);
        acc += v;
    }
    if (curg >= 0) atomicAdd(&pooled[(size_t)curg * DD + f], acc);
}

// ================= jumping-knowledge readout =================
__global__ void readout_k(const float* __restrict__ pooled,
                          const float* __restrict__ Wp, const float* __restrict__ bp,
                          float* __restrict__ out)
{
    int gc = blockIdx.x * blockDim.x + threadIdx.x;
    if (gc >= GG * CC) return;
    int g = gc / CC, c = gc - g * CC;
    float acc = 0.f;
    for (int l = 0; l < LL; ++l) {
        acc += bp[l * CC + c];
        const float* p  = pooled + ((size_t)l * GG + g) * DD;
        const float* wv = Wp + (size_t)l * DD * CC + c;
        #pragma unroll 8
        for (int f = 0; f < DD; ++f) acc = fmaf(p[f], wv[f * CC], acc);
    }
    out[gc] = acc;
}

extern "C" void kernel_launch(void* const* d_in, const int* in_sizes, int n_in,
                              void* d_out, int out_size, void* d_ws, size_t ws_size,
                              hipStream_t stream) {
    const float* x     = (const float*)d_in[0];
    const int*   ei    = (const int*)d_in[1];
    const int*   batch = (const int*)d_in[2];
    const float* eps   = (const float*)d_in[3];
    const float* W1    = (const float*)d_in[4];
    const float* b1    = (const float*)d_in[5];
    const float* g1    = (const float*)d_in[6];
    const float* be1   = (const float*)d_in[7];
    const float* W2    = (const float*)d_in[8];
    const float* b2    = (const float*)d_in[9];
    const float* gout  = (const float*)d_in[10];
    const float* beout = (const float*)d_in[11];
    const float* Wp    = (const float*)d_in[12];
    const float* bp    = (const float*)d_in[13];
    float* out = (float*)d_out;

    // ---- workspace layout (16B-aligned sections) ----
    unsigned int* stage = (unsigned int*)d_ws;          // EE*4
    int* adj   = (int*)(stage + EE);                    // EE*4
    int* offs  = adj + EE;                              // (NPAD+256)
    int* bh    = offs + NPAD + 256;                     // 400
    int* bo    = bh + 400;                              // 400
    int* bcur  = bo + 400;                              // 400
    float* pooled = (float*)(bcur + 400);               // LL*GG*DD
    float* stats1 = pooled + (size_t)LL * GG * DD;      // SC*128
    float* stats2 = stats1 + SC * 128;                  // SC*128
    unsigned short* hb  = (unsigned short*)(stats2 + SC * 128);
    unsigned short* z1b = hb + N64;
    unsigned short* z2b = z1b + N64;
    unsigned short* wt  = z2b + N64;                    // 8*4096

    // ---- prep + layer-0 pooling ----
    hipMemsetAsync(pooled, 0, ((size_t)LL * GG * DD + 2 * SC * 128) * sizeof(float), stream);
    prep_x_pool_k<<<(NN + 63) / 64, 256, 0, stream>>>(x, batch, hb, pooled);
    prep_w_k<<<8, 256, 0, stream>>>(W1, W2, wt);

    // ---- CSR build via LDS-staged two-pass partition ----
    hipMemsetAsync(bh, 0, NB * sizeof(int), stream);
    bhist_k<<<512, 256, 0, stream>>>(ei, bh);
    bscan_k<<<1, 512, 0, stream>>>(bh, bo, bcur);
    partition_k<<<(EE + PCH - 1) / PCH, 256, 0, stream>>>(ei, bcur, stage);
    bucket_csr_k<<<NB, 256, 0, stream>>>(stage, bo, adj, offs);

    const int gemm_grid = (NN + 63) / 64;
    const int node_grid = (NN + 63) / 64;
    for (int l = 0; l < LL - 1; ++l) {
        layer1_k<<<gemm_grid, 256, 0, stream>>>(
            hb, adj, offs, eps, l, wt + (size_t)l * 4096, b1 + l * DD, z1b, stats1, stats2);
        layer2_k<<<gemm_grid, 256, 0, stream>>>(
            z1b, stats1, g1, be1, l * DD, wt + (size_t)(4 + l) * 4096, b2 + l * DD, z2b, stats2);
        layer3_k<<<node_grid, 256, 0, stream>>>(
            z2b, stats2, gout, beout, l * DD, batch, hb,
            pooled + (size_t)(l + 1) * GG * DD, stats1);
    }
    readout_k<<<(GG * CC + 255) / 256, 256, 0, stream>>>(pooled, Wp, bp, out);
}

// Round 9
// 641.095 us; speedup vs baseline: 1.3880x; 1.0878x over previous
//
#include <hip/hip_runtime.h>

#define NN 100000
#define EE 1600000
#define DD 64
#define CC 10
#define GG 512
#define LL 5
#define NPAD 100352            // 392*256
#define N64 (NN * DD)
#define NB 392                 // coarse buckets (256 nodes each)
#define PCH 4096               // edges per partition block
#define BCAP 6144              // per-bucket LDS capacity (mean 4082, >30 sigma)
#define SC 8                   // BN stats shadow copies

typedef short bf16x8 __attribute__((ext_vector_type(8)));
typedef float f32x4  __attribute__((ext_vector_type(4)));
union U16 { uint4 u; bf16x8 h; };

__device__ __forceinline__ float bits2f(unsigned int b) { return __uint_as_float(b); }
__device__ __forceinline__ float bf2f(unsigned short s) { return __uint_as_float((unsigned int)s << 16); }
__device__ __forceinline__ unsigned short f2bf_rne(float v) {
    unsigned int b = __float_as_uint(v);
    return (unsigned short)((b + 0x7fffu + ((b >> 16) & 1u)) >> 16);
}
__device__ __forceinline__ void unpack8(uint4 u, float* f) {
    f[0] = bits2f(u.x << 16); f[1] = bits2f(u.x & 0xffff0000u);
    f[2] = bits2f(u.y << 16); f[3] = bits2f(u.y & 0xffff0000u);
    f[4] = bits2f(u.z << 16); f[5] = bits2f(u.z & 0xffff0000u);
    f[6] = bits2f(u.w << 16); f[7] = bits2f(u.w & 0xffff0000u);
}
__device__ __forceinline__ uint4 pack8(const float* f) {
    uint4 u;
    u.x = (unsigned int)f2bf_rne(f[0]) | ((unsigned int)f2bf_rne(f[1]) << 16);
    u.y = (unsigned int)f2bf_rne(f[2]) | ((unsigned int)f2bf_rne(f[3]) << 16);
    u.z = (unsigned int)f2bf_rne(f[4]) | ((unsigned int)f2bf_rne(f[5]) << 16);
    u.w = (unsigned int)f2bf_rne(f[6]) | ((unsigned int)f2bf_rne(f[7]) << 16);
    return u;
}
__device__ __forceinline__ void acc8(uint4 u, float* a) {
    float t[8];
    unpack8(u, t);
    #pragma unroll
    for (int k = 0; k < 8; ++k) a[k] += t[k];
}

// ======== prep: x fp32 -> bf16 h, fused layer-0 segmented pooling ========
__global__ __launch_bounds__(256) void prep_x_pool_k(
    const float* __restrict__ x, const int* __restrict__ batch,
    unsigned short* __restrict__ hb, float* __restrict__ pooled)
{
    int t = threadIdx.x;
    int f = t & 63;
    int q = t >> 6;
    int n0 = blockIdx.x * 64 + q * 16;
    int nmax = NN - n0; if (nmax > 16) nmax = 16;
    float acc = 0.f;
    int curg = -1;
    #pragma unroll 4
    for (int i = 0; i < nmax; ++i) {
        int n = n0 + i;
        int g = batch[n];
        if (g != curg) {
            if (curg >= 0) atomicAdd(&pooled[(size_t)curg * DD + f], acc);
            acc = 0.f; curg = g;
        }
        float v = x[(size_t)n * DD + f];
        hb[(size_t)n * DD + f] = f2bf_rne(v);
        acc += v;
    }
    if (curg >= 0) atomicAdd(&pooled[(size_t)curg * DD + f], acc);
}

// ================= prep: W -> transposed bf16 =================
__global__ __launch_bounds__(256) void prep_w_k(const float* __restrict__ W1,
                                                const float* __restrict__ W2,
                                                unsigned short* __restrict__ wt) {
    int mat = blockIdx.x;
    const float* src = (mat < 4) ? (W1 + (size_t)mat * 4096)
                                 : (W2 + (size_t)(mat - 4) * 4096);
    for (int idx = threadIdx.x; idx < 4096; idx += 256) {
        int c = idx >> 6, k = idx & 63;
        wt[(size_t)mat * 4096 + c * 64 + k] = f2bf_rne(src[k * 64 + c]);
    }
}

// ================= CSR build: coarse hist =================
__global__ __launch_bounds__(256) void bhist_k(const int* __restrict__ ei,
                                               int* __restrict__ bh) {
    __shared__ int cnt[NB];
    for (int i = threadIdx.x; i < NB; i += 256) cnt[i] = 0;
    __syncthreads();
    int stride = gridDim.x * 256;
    for (int e = blockIdx.x * 256 + threadIdx.x; e < EE; e += stride)
        atomicAdd(&cnt[ei[EE + e] >> 8], 1);
    __syncthreads();
    for (int i = threadIdx.x; i < NB; i += 256)
        if (cnt[i]) atomicAdd(&bh[i], cnt[i]);
}

// ================= coarse scan =================
__global__ __launch_bounds__(512) void bscan_k(const int* __restrict__ bh,
                                               int* __restrict__ bo,
                                               int* __restrict__ bcur) {
    __shared__ int s[512];
    int t = threadIdx.x;
    int v = (t < NB) ? bh[t] : 0;
    s[t] = v;
    __syncthreads();
    for (int d = 1; d < 512; d <<= 1) {
        int a = (t >= d) ? s[t - d] : 0;
        __syncthreads();
        s[t] += a;
        __syncthreads();
    }
    int excl = s[t] - v;
    if (t < NB) { bo[t] = excl; bcur[t] = excl; }
    if (t == NB - 1) bo[NB] = excl + v;
}

// ============ partition edges into bucket-contiguous staging ============
// stage entry: src (bits 0..16) | dst-local-in-bucket (bits 17..24)
__global__ __launch_bounds__(256) void partition_k(const int* __restrict__ ei,
                                                   int* __restrict__ bcur,
                                                   unsigned int* __restrict__ stage) {
    __shared__ int hist[NB];
    __shared__ int base[NB];
    __shared__ int gbase[NB];
    __shared__ int cnt2[NB];
    __shared__ int scanbuf[512];
    __shared__ unsigned int pairs[PCH];
    __shared__ unsigned short pbkt[PCH];
    int t = threadIdx.x;
    int e0 = blockIdx.x * PCH;
    int nE = EE - e0; if (nE > PCH) nE = PCH;

    for (int i = t; i < NB; i += 256) { hist[i] = 0; cnt2[i] = 0; }
    __syncthreads();

    int mys[16], myd[16];
    #pragma unroll
    for (int i = 0; i < 16; ++i) {
        int idx = i * 256 + t;
        if (idx < nE) {
            mys[i] = ei[e0 + idx];
            myd[i] = ei[EE + e0 + idx];
            atomicAdd(&hist[myd[i] >> 8], 1);
        } else myd[i] = -1;
    }
    __syncthreads();

    scanbuf[t]       = (t < NB) ? hist[t] : 0;
    scanbuf[t + 256] = (t + 256 < NB) ? hist[t + 256] : 0;
    __syncthreads();
    for (int d = 1; d < 512; d <<= 1) {
        int a0 = (t >= d) ? scanbuf[t - d] : 0;
        int a1 = ((t + 256) >= d) ? scanbuf[t + 256 - d] : 0;
        __syncthreads();
        scanbuf[t] += a0;
        scanbuf[t + 256] += a1;
        __syncthreads();
    }
    if (t < NB)       base[t]       = scanbuf[t] - hist[t];
    if (t + 256 < NB) base[t + 256] = scanbuf[t + 256] - hist[t + 256];
    __syncthreads();

    #pragma unroll
    for (int i = 0; i < 16; ++i) {
        if (myd[i] >= 0) {
            int b = myd[i] >> 8;
            int p = base[b] + atomicAdd(&cnt2[b], 1);
            pairs[p] = (unsigned)mys[i] | ((unsigned)(myd[i] & 255) << 17);
            pbkt[p] = (unsigned short)b;
        }
    }
    __syncthreads();
    for (int i = t; i < NB; i += 256)
        if (hist[i]) gbase[i] = atomicAdd(&bcur[i], hist[i]);
    __syncthreads();
    for (int p = t; p < nE; p += 256) {
        int b = pbkt[p];
        stage[gbase[b] + (p - base[b])] = pairs[p];
    }
}

// ============ per-bucket CSR: adj + offs, all in LDS ============
__global__ __launch_bounds__(256) void bucket_csr_k(const unsigned int* __restrict__ stage,
                                                    const int* __restrict__ bo,
                                                    int* __restrict__ adj,
                                                    int* __restrict__ offs) {
    __shared__ int deg[256];
    __shared__ int sb[256];
    __shared__ int nb_[256];
    __shared__ int c2[256];
    __shared__ int loc[BCAP];
    int b = blockIdx.x;
    int s0 = bo[b], s1 = bo[b + 1];
    int cnt = s1 - s0;
    int t = threadIdx.x;

    deg[t] = 0;
    __syncthreads();
    for (int i = t; i < cnt; i += 256) atomicAdd(&deg[(stage[s0 + i] >> 17) & 255], 1);
    __syncthreads();
    sb[t] = deg[t];
    __syncthreads();
    for (int d = 1; d < 256; d <<= 1) {
        int a = (t >= d) ? sb[t - d] : 0;
        __syncthreads();
        sb[t] += a;
        __syncthreads();
    }
    int nbase = sb[t] - deg[t];
    nb_[t] = nbase;
    c2[t] = 0;
    offs[b * 256 + t] = s0 + nbase;
    __syncthreads();

    if (cnt <= BCAP) {
        for (int i = t; i < cnt; i += 256) {
            unsigned int pr = stage[s0 + i];
            int ln = (pr >> 17) & 255;
            int p = nb_[ln] + atomicAdd(&c2[ln], 1);
            loc[p] = (int)(pr & 0x1FFFF);
        }
        __syncthreads();
        for (int i = t; i < cnt; i += 256) adj[s0 + i] = loc[i];
    } else {            // statistically unreachable fallback
        for (int i = t; i < cnt; i += 256) {
            unsigned int pr = stage[s0 + i];
            int ln = (pr >> 17) & 255;
            int p = nb_[ln] + atomicAdd(&c2[ln], 1);
            adj[s0 + p] = (int)(pr & 0x1FFFF);
        }
    }
}

// ========== K1: 8-lane-group gather (R5 structure) -> LDS -> MFMA GEMM1 + stats1 ==========
// block=256: VGPR 32 / 52% occupancy measured optimal (R5: 61µs vs tandem/unroll4/wave-per-node all worse)
__global__ __launch_bounds__(256) void layer1_k(
    const unsigned short* __restrict__ hb, const int* __restrict__ adj,
    const int* __restrict__ offs, const float* __restrict__ epsArr, int l,
    const unsigned short* __restrict__ wtm, const float* __restrict__ bias,
    unsigned short* __restrict__ z1, float* __restrict__ stats1,
    float* __restrict__ stats2z)
{
    __shared__ unsigned short aLDS[64 * 64];   // 8KB, XOR-swizzled 16B units
    const int t = threadIdx.x;
    const int lane = t & 63;
    const int w = t >> 6;
    const int n15 = lane & 15;
    const int quad = lane >> 4;

    if (blockIdx.x < SC && t < 128) stats2z[blockIdx.x * 128 + t] = 0.f;

    const float epsv = 1.0f + epsArr[l];
    const int c8 = lane & 7;
    // ---- gather 16 rows per wave (8 lanes/node, 2 iterations), unroll-2 ----
    #pragma unroll
    for (int it = 0; it < 2; ++it) {
        int lr = w * 16 + it * 8 + (lane >> 3);
        int n = blockIdx.x * 64 + lr;
        float acc[8] = {0.f,0.f,0.f,0.f,0.f,0.f,0.f,0.f};
        if (n < NN) {
            uint4 a = *(const uint4*)(hb + (size_t)n * DD + c8 * 8);
            unpack8(a, acc);
            #pragma unroll
            for (int j2 = 0; j2 < 8; ++j2) acc[j2] *= epsv;
            int j = offs[n], end = offs[n + 1];
            for (; j + 1 < end; j += 2) {
                int s0 = adj[j], s1 = adj[j + 1];
                uint4 v0 = *(const uint4*)(hb + (size_t)s0 * DD + c8 * 8);
                uint4 v1 = *(const uint4*)(hb + (size_t)s1 * DD + c8 * 8);
                acc8(v0, acc);
                acc8(v1, acc);
            }
            if (j < end) {
                uint4 v0 = *(const uint4*)(hb + (size_t)adj[j] * DD + c8 * 8);
                acc8(v0, acc);
            }
        }
        int pu = c8 ^ (lr & 7);
        *(uint4*)(aLDS + lr * 64 + pu * 8) = pack8(acc);
    }
    // rows are wave-private; compiler inserts lgkmcnt before the reads below

    // ---- A fragments from LDS (swizzled) ----
    U16 afr[2];
    int lr2 = w * 16 + n15;
    #pragma unroll
    for (int ks = 0; ks < 2; ++ks) {
        int pu = (ks * 4 + quad) ^ (lr2 & 7);
        afr[ks].u = *(const uint4*)(aLDS + lr2 * 64 + pu * 8);
    }
    // ---- B fragments from global (after gather: keeps VGPR at 32) ----
    U16 bfr[4][2];
    #pragma unroll
    for (int ct = 0; ct < 4; ++ct)
        #pragma unroll
        for (int ks = 0; ks < 2; ++ks)
            bfr[ct][ks].u = *(const uint4*)(wtm + (size_t)(ct * 16 + n15) * 64 + ks * 32 + quad * 8);

    const int rowg0 = blockIdx.x * 64 + w * 16;
    const int copy = blockIdx.x & (SC - 1);
    #pragma unroll
    for (int ct = 0; ct < 4; ++ct) {
        f32x4 acc = {0.f, 0.f, 0.f, 0.f};
        acc = __builtin_amdgcn_mfma_f32_16x16x32_bf16(afr[0].h, bfr[ct][0].h, acc, 0, 0, 0);
        acc = __builtin_amdgcn_mfma_f32_16x16x32_bf16(afr[1].h, bfr[ct][1].h, acc, 0, 0, 0);
        int col = ct * 16 + n15;
        float bcol = bias[col];
        float s = 0.f, ss = 0.f;
        #pragma unroll
        for (int r = 0; r < 4; ++r) {
            int rg = rowg0 + quad * 4 + r;
            float v = acc[r] + bcol;
            if (rg < NN) {
                z1[(size_t)rg * DD + col] = f2bf_rne(v);
                s += v;
                ss = fmaf(v, v, ss);
            }
        }
        s  += __shfl_xor(s, 16, 64);  s  += __shfl_xor(s, 32, 64);
        ss += __shfl_xor(ss, 16, 64); ss += __shfl_xor(ss, 32, 64);
        if (lane < 16) {
            atomicAdd(&stats1[copy * 128 + ct * 16 + lane], s);
            atomicAdd(&stats1[copy * 128 + 64 + ct * 16 + lane], ss);
        }
    }
}

// ========== K2: inline BN1 + MFMA GEMM2 + stats2 ==========
__global__ __launch_bounds__(256) void layer2_k(
    const unsigned short* __restrict__ z1, const float* __restrict__ stats1,
    const float* __restrict__ gamma, const float* __restrict__ beta, int off,
    const unsigned short* __restrict__ wtm, const float* __restrict__ bias,
    unsigned short* __restrict__ z2, float* __restrict__ stats2)
{
    __shared__ float ssS[128];
    const int t = threadIdx.x;
    const int lane = t & 63;
    const int w = t >> 6;
    const int n15 = lane & 15;
    const int quad = lane >> 4;
    const int rowg0 = blockIdx.x * 64 + w * 16;

    // ---- issue independent global loads BEFORE the stats barrier ----
    U16 bfr[4][2];
    #pragma unroll
    for (int ct = 0; ct < 4; ++ct)
        #pragma unroll
        for (int ks = 0; ks < 2; ++ks)
            bfr[ct][ks].u = *(const uint4*)(wtm + (size_t)(ct * 16 + n15) * 64 + ks * 32 + quad * 8);

    int arow = rowg0 + n15;
    int arowc = (arow < NN) ? arow : (NN - 1);
    uint4 raw[2];
    #pragma unroll
    for (int ks = 0; ks < 2; ++ks)
        raw[ks] = *(const uint4*)(z1 + (size_t)arowc * DD + ks * 32 + quad * 8);

    if (t < 64) {
        float S = 0.f, SS = 0.f;
        #pragma unroll
        for (int c = 0; c < SC; ++c) { S += stats1[c * 128 + t]; SS += stats1[c * 128 + 64 + t]; }
        float inv_n = 1.0f / (float)NN;
        float mean = S * inv_n;
        float var  = SS * inv_n - mean * mean;
        float sc = gamma[off + t] * rsqrtf(var + 1e-5f);
        ssS[t] = sc;
        ssS[64 + t] = beta[off + t] - sc * mean;
    }
    __syncthreads();

    U16 afr[2];
    #pragma unroll
    for (int ks = 0; ks < 2; ++ks) {
        float f[8];
        unpack8(raw[ks], f);
        int k0 = ks * 32 + quad * 8;
        #pragma unroll
        for (int j = 0; j < 8; ++j)
            f[j] = fmaxf(fmaf(ssS[k0 + j], f[j], ssS[64 + k0 + j]), 0.f);
        afr[ks].u = pack8(f);
    }

    const int copy = blockIdx.x & (SC - 1);
    #pragma unroll
    for (int ct = 0; ct < 4; ++ct) {
        f32x4 acc = {0.f, 0.f, 0.f, 0.f};
        acc = __builtin_amdgcn_mfma_f32_16x16x32_bf16(afr[0].h, bfr[ct][0].h, acc, 0, 0, 0);
        acc = __builtin_amdgcn_mfma_f32_16x16x32_bf16(afr[1].h, bfr[ct][1].h, acc, 0, 0, 0);
        int col = ct * 16 + n15;
        float bcol = bias[col];
        float s = 0.f, ss = 0.f;
        #pragma unroll
        for (int r = 0; r < 4; ++r) {
            int rg = rowg0 + quad * 4 + r;
            float v = acc[r] + bcol;
            if (rg < NN) {
                z2[(size_t)rg * DD + col] = f2bf_rne(v);
                s += v;
                ss = fmaf(v, v, ss);
            }
        }
        s  += __shfl_xor(s, 16, 64);  s  += __shfl_xor(s, 32, 64);
        ss += __shfl_xor(ss, 16, 64); ss += __shfl_xor(ss, 32, 64);
        if (lane < 16) {
            atomicAdd(&stats2[copy * 128 + ct * 16 + lane], s);
            atomicAdd(&stats2[copy * 128 + 64 + ct * 16 + lane], ss);
        }
    }
}

// ========== K3: inline BN2 + ReLU + hb write + segmented pool ==========
__global__ __launch_bounds__(256) void layer3_k(
    const unsigned short* __restrict__ z2, const float* __restrict__ stats2,
    const float* __restrict__ gamma, const float* __restrict__ beta, int off,
    const int* __restrict__ batch, unsigned short* __restrict__ hout,
    float* __restrict__ pooled, float* __restrict__ stats1z)
{
    __shared__ float ssS[128];
    int t = threadIdx.x;
    if (blockIdx.x < SC && t < 128) stats1z[blockIdx.x * 128 + t] = 0.f;
    if (t < 64) {
        float S = 0.f, SS = 0.f;
        #pragma unroll
        for (int c = 0; c < SC; ++c) { S += stats2[c * 128 + t]; SS += stats2[c * 128 + 64 + t]; }
        float inv_n = 1.0f / (float)NN;
        float mean = S * inv_n;
        float var  = SS * inv_n - mean * mean;
        float sc = gamma[off + t] * rsqrtf(var + 1e-5f);
        ssS[t] = sc;
        ssS[64 + t] = beta[off + t] - sc * mean;
    }
    __syncthreads();

    int f = t & 63;
    int q = t >> 6;
    int n0 = blockIdx.x * 64 + q * 16;
    int nmax = NN - n0; if (nmax > 16) nmax = 16;
    float sc = ssS[f], sh = ssS[64 + f];
    float acc = 0.f;
    int curg = -1;
    #pragma unroll 4
    for (int i = 0; i < nmax; ++i) {
        int n = n0 + i;
        int g = batch[n];
        if (g != curg) {
            if (curg >= 0) atomicAdd(&pooled[(size_t)curg * DD + f], acc);
            acc = 0.f; curg = g;
        }
        float v = bf2f(z2[(size_t)n * DD + f]);
        v = fmaxf(fmaf(sc, v, sh), 0.f);
        hout[(size_t)n * DD + f] = f2bf_rne(v);
        acc += v;
    }
    if (curg >= 0) atomicAdd(&pooled[(size_t)curg * DD + f], acc);
}

// ================= jumping-knowledge readout =================
__global__ void readout_k(const float* __restrict__ pooled,
                          const float* __restrict__ Wp, const float* __restrict__ bp,
                          float* __restrict__ out)
{
    int gc = blockIdx.x * blockDim.x + threadIdx.x;
    if (gc >= GG * CC) return;
    int g = gc / CC, c = gc - g * CC;
    float acc = 0.f;
    for (int l = 0; l < LL; ++l) {
        acc += bp[l * CC + c];
        const float* p  = pooled + ((size_t)l * GG + g) * DD;
        const float* wv = Wp + (size_t)l * DD * CC + c;
        #pragma unroll 8
        for (int f = 0; f < DD; ++f) acc = fmaf(p[f], wv[f * CC], acc);
    }
    out[gc] = acc;
}

extern "C" void kernel_launch(void* const* d_in, const int* in_sizes, int n_in,
                              void* d_out, int out_size, void* d_ws, size_t ws_size,
                              hipStream_t stream) {
    const float* x     = (const float*)d_in[0];
    const int*   ei    = (const int*)d_in[1];
    const int*   batch = (const int*)d_in[2];
    const float* eps   = (const float*)d_in[3];
    const float* W1    = (const float*)d_in[4];
    const float* b1    = (const float*)d_in[5];
    const float* g1    = (const float*)d_in[6];
    const float* be1   = (const float*)d_in[7];
    const float* W2    = (const float*)d_in[8];
    const float* b2    = (const float*)d_in[9];
    const float* gout  = (const float*)d_in[10];
    const float* beout = (const float*)d_in[11];
    const float* Wp    = (const float*)d_in[12];
    const float* bp    = (const float*)d_in[13];
    float* out = (float*)d_out;

    // ---- workspace layout (16B-aligned sections) ----
    unsigned int* stage = (unsigned int*)d_ws;          // EE*4
    int* adj   = (int*)(stage + EE);                    // EE*4
    int* offs  = adj + EE;                              // (NPAD+256)
    int* bh    = offs + NPAD + 256;                     // 400
    int* bo    = bh + 400;                              // 400
    int* bcur  = bo + 400;                              // 400
    float* pooled = (float*)(bcur + 400);               // LL*GG*DD
    float* stats1 = pooled + (size_t)LL * GG * DD;      // SC*128
    float* stats2 = stats1 + SC * 128;                  // SC*128
    unsigned short* hb  = (unsigned short*)(stats2 + SC * 128);
    unsigned short* z1b = hb + N64;
    unsigned short* z2b = z1b + N64;
    unsigned short* wt  = z2b + N64;                    // 8*4096

    // ---- prep + layer-0 pooling ----
    hipMemsetAsync(pooled, 0, ((size_t)LL * GG * DD + 2 * SC * 128) * sizeof(float), stream);
    prep_x_pool_k<<<(NN + 63) / 64, 256, 0, stream>>>(x, batch, hb, pooled);
    prep_w_k<<<8, 256, 0, stream>>>(W1, W2, wt);

    // ---- CSR build via LDS-staged two-pass partition ----
    hipMemsetAsync(bh, 0, NB * sizeof(int), stream);
    bhist_k<<<512, 256, 0, stream>>>(ei, bh);
    bscan_k<<<1, 512, 0, stream>>>(bh, bo, bcur);
    partition_k<<<(EE + PCH - 1) / PCH, 256, 0, stream>>>(ei, bcur, stage);
    bucket_csr_k<<<NB, 256, 0, stream>>>(stage, bo, adj, offs);

    const int gemm_grid = (NN + 63) / 64;
    const int node_grid = (NN + 63) / 64;
    for (int l = 0; l < LL - 1; ++l) {
        layer1_k<<<gemm_grid, 256, 0, stream>>>(
            hb, adj, offs, eps, l, wt + (size_t)l * 4096, b1 + l * DD, z1b, stats1, stats2);
        layer2_k<<<gemm_grid, 256, 0, stream>>>(
            z1b, stats1, g1, be1, l * DD, wt + (size_t)(4 + l) * 4096, b2 + l * DD, z2b, stats2);
        layer3_k<<<node_grid, 256, 0, stream>>>(
            z2b, stats2, gout, beout, l * DD, batch, hb,
            pooled + (size_t)(l + 1) * GG * DD, stats1);
    }
    readout_k<<<(GG * CC + 255) / 256, 256, 0, stream>>>(pooled, Wp, bp, out);
}